// Round 13
// baseline (87.549 us; speedup 1.0000x reference)
//
#include <hip/hip_runtime.h>
#include <hip/hip_bf16.h>
#include <math.h>

// SupConLoss, B=4096 V=2 D=128, N=8192.
// loss = (1/N) [ sum_i log(sum_{j!=i} exp(n_i.n_j/T)) - 2*sum_b spos_b ]
// Round 13: SINGLE-BARRIER main kernel. R11/R12 evidence: per-tile barriers
// (8x vmcnt(0)+s_barrier) are the last structural stall — every tile pays
// full DMA latency, block-wide. Fix: stage the block's whole 64 KB B-chunk
// via global_load_lds up front, ONE __syncthreads, then barrier-free compute
// (waves independent); per-wave col-sums stored straight to global (no end
// barrier). LDS 64 KB -> 2 blocks/CU.

constexpr int   Bsz   = 4096;
constexpr int   Nrows = 8192;
constexpr int   Dd    = 128;
constexpr float TEMPf = 0.07f;
constexpr float EPSN  = 1e-8f;
constexpr float SCALE = 1.4426950408889634f / 0.07f;  // log2(e)/T
constexpr float LN2   = 0.6931471805599453f;

constexpr int CHUNKS     = 32;                 // col chunks (grid.x)
constexpr int CHUNK_COLS = Nrows / CHUNKS;     // 256
constexpr int TILES      = CHUNK_COLS / 32;    // 8 col-groups of 32
constexpr int ROWS_BLK   = 256;                // rows per block (4 waves x 64)
constexpr int YG         = Nrows / ROWS_BLK;   // 32 (grid.y)
constexpr int WSLICES    = YG * 4;             // 128 per-wave partial slices
constexpr int PREPBLKS   = Bsz / 4;            // 1024

typedef __attribute__((ext_vector_type(8)))  short bf16x8;   // 8 bf16 = 4 VGPRs
typedef __attribute__((ext_vector_type(16))) float floatx16; // MFMA 32x32 C/D

// Fragment-major n: row r = g*32+lo stores its 256 B at
// g*8192 + kc*1024 + hi*512 + lo*16. Wave fragment load (g,kc) =
// base + g*8192 + kc*1024 + lane*16 — coalesced 1 KB; global_load_lds
// placement (lds_base + lane*16) reproduces it in LDS verbatim.

// ws layout (bytes):
//   0x000000  nF   fragment-major bf16 n      2 MB
//   0x200000  partialW f32[128][8192]         4 MB  (per-wave col sums)
//   0x600000  sposPart f32[1024]              4 KB
constexpr size_t OFF_PART = 0x200000;
constexpr size_t OFF_SPOS = 0x600000;

__device__ __forceinline__ void gld_lds16(const void* g, void* l) {
    __builtin_amdgcn_global_load_lds(
        (const __attribute__((address_space(1))) void*)g,
        (__attribute__((address_space(3))) void*)l, 16, 0, 0);
}

// ------------- prep: normalize both views -> nF + per-block spos sums ----------
__global__ void prep_k(const float* __restrict__ f,
                       char* __restrict__ nF,
                       float* __restrict__ sposPart,
                       float* __restrict__ out) {
    __shared__ float sred[4];
    int tid  = threadIdx.x;
    int wid  = tid >> 6;
    int lane = tid & 63;
    int b    = blockIdx.x * 4 + wid;
    if (blockIdx.x == 0 && tid == 0) out[0] = 0.f;   // final_k accumulates

    const float* s0 = f + (size_t)(b * 2) * Dd;       // features[b, 0, :]
    float2 x = *(const float2*)(s0 + lane * 2);       // view 0
    float2 y = *(const float2*)(s0 + Dd + lane * 2);  // view 1
    float ss0 = x.x * x.x + x.y * x.y;
    float ss1 = y.x * y.x + y.y * y.y;
    float dt  = x.x * y.x + x.y * y.y;
    #pragma unroll
    for (int off = 32; off; off >>= 1) {
        ss0 += __shfl_xor(ss0, off);
        ss1 += __shfl_xor(ss1, off);
        dt  += __shfl_xor(dt,  off);
    }
    float inv0 = 1.0f / fmaxf(sqrtf(ss0), EPSN);
    float inv1 = 1.0f / fmaxf(sqrtf(ss1), EPSN);

    // lane holds k = 2*lane..2*lane+1 -> piece (kc=lane>>3, hi=(lane>>2)&1),
    // byte offset inside piece = (lane&3)*4
    size_t poff = (size_t)(lane >> 3) * 1024 + ((lane >> 2) & 1) * 512
                + (lane & 3) * 4;

    __hip_bfloat162 h;
    h.x = __float2bfloat16(x.x * inv0);
    h.y = __float2bfloat16(x.y * inv0);
    *(__hip_bfloat162*)(nF + (size_t)(b >> 5) * 8192 + (b & 31) * 16 + poff) = h;
    int r1 = Bsz + b;
    h.x = __float2bfloat16(y.x * inv1);
    h.y = __float2bfloat16(y.y * inv1);
    *(__hip_bfloat162*)(nF + (size_t)(r1 >> 5) * 8192 + (r1 & 31) * 16 + poff) = h;

    if (lane == 0) sred[wid] = dt * inv0 * inv1 / TEMPf;
    __syncthreads();
    if (tid == 0) sposPart[blockIdx.x] = sred[0] + sred[1] + sred[2] + sred[3];
}

// ------------- main: single-barrier async-LDS GEMM + exp2 + col sums -----------
// Grid (32 chunks, 32 row-groups). Stage the whole 64 KB B-chunk (8 col-groups)
// via global_load_lds, ONE barrier, then barrier-free compute: per tile
// 16 MFMA + 32 exp2, col-sum scalar per lane, per-wave store to partialW.
__global__ __launch_bounds__(256, 2)
void main_k(const char* __restrict__ nF, float* __restrict__ partialW) {
    __shared__ char buf[TILES][8192];   // 64 KB
    const int tid  = threadIdx.x;
    const int wid  = tid >> 6;
    const int lane = tid & 63;
    const int lo   = lane & 31;
    const int hi   = lane >> 5;
    const int gy   = blockIdx.y;
    const int rbase = gy * ROWS_BLK + wid * 64;          // wave's 64 rows
    const int cbase = blockIdx.x * CHUNK_COLS;           // 256-aligned
    const int cg0   = cbase >> 5;                        // first col group

    // stage ALL 8 col-groups: wave w DMAs groups 2w, 2w+1 (16 instrs)
    {
        const char* gsrc = nF + (size_t)cg0 * 8192;
        #pragma unroll
        for (int g = 0; g < 2; g++) {
            int t = wid * 2 + g;
            #pragma unroll
            for (int kc = 0; kc < 8; kc++)
                gld_lds16(gsrc + (size_t)t * 8192 + kc * 1024 + lane * 16,
                          &buf[t][kc * 1024]);
        }
    }

    // A fragments while DMA flies: two 32-row groups, 8 coalesced loads each
    bf16x8 afrag[2][8];
    #pragma unroll
    for (int s = 0; s < 2; s++) {
        const char* ag = nF + (size_t)((rbase + s * 32) >> 5) * 8192 + lane * 16;
        #pragma unroll
        for (int kc = 0; kc < 8; kc++)
            afrag[s][kc] = *(const bf16x8*)(ag + kc * 1024);
    }

    __syncthreads();   // the ONLY barrier: all DMAs drained, buf complete

    floatx16 zero = {};
    float* wrow = partialW + (size_t)(gy * 4 + wid) * Nrows + cbase;

    #pragma unroll 1
    for (int t = 0; t < TILES; t++) {
        floatx16 acc0 = zero, acc1 = zero;
        #pragma unroll
        for (int kc = 0; kc < 8; kc++) {
            bf16x8 bf = *(const bf16x8*)&buf[t][kc * 1024 + lane * 16];
            acc0 = __builtin_amdgcn_mfma_f32_32x32x16_bf16(afrag[0][kc], bf, acc0, 0, 0, 0);
            acc1 = __builtin_amdgcn_mfma_f32_32x32x16_bf16(afrag[1][kc], bf, acc1, 0, 0, 0);
        }

        // epilogue: exp2, diag mask (wave-uniform branch), COLUMN sums
        const int cb32 = cbase + t * 32;
        float cs = 0.f;
        #pragma unroll
        for (int s = 0; s < 2; s++) {
            const floatx16& acc = s ? acc1 : acc0;
            if (cb32 == rbase + s * 32) {     // taken <=1 of 16 (s,t) combos
                #pragma unroll
                for (int r = 0; r < 16; r++) {
                    float e = __builtin_amdgcn_exp2f(acc[r] * SCALE);
                    // C/D layout: col=lo, row_local=(r&3)+8*(r>>2)+4*hi
                    if (lo == ((r & 3) + 8 * (r >> 2) + 4 * hi)) e = 0.f;
                    cs += e;
                }
            } else {
                #pragma unroll
                for (int r = 0; r < 16; r++)
                    cs += __builtin_amdgcn_exp2f(acc[r] * SCALE);
            }
        }
        cs += __shfl_xor(cs, 32);             // fold the two row-half lanes
        if (hi == 0) wrow[t * 32 + lo] = cs;  // per-wave slice, no sync needed
    }
}

// ------------- finalize: 32 blocks; atomicAdd the scalar -----------------------
// se[col] = sum over 128 wave-slices (col sum == row sum of exp matrix)
__global__ __launch_bounds__(256)
void final_k(const float* __restrict__ partialW, const float* __restrict__ sposPart,
             float* __restrict__ out) {
    __shared__ float red[4];
    int tid = threadIdx.x;
    int r = blockIdx.x * 256 + tid;
    float se = 0.f;
    #pragma unroll 4
    for (int p = 0; p < WSLICES; p++) se += partialW[(size_t)p * Nrows + r];
    float acc = __builtin_amdgcn_logf(se) * LN2;   // v_log_f32 is log2
    if (tid < 32) acc -= 2.f * sposPart[blockIdx.x * 32 + tid];
    #pragma unroll
    for (int off = 32; off; off >>= 1) acc += __shfl_xor(acc, off);
    if ((tid & 63) == 0) red[tid >> 6] = acc;
    __syncthreads();
    if (tid == 0)
        atomicAdd(out, (red[0] + red[1] + red[2] + red[3]) / (float)Nrows);
}

extern "C" void kernel_launch(void* const* d_in, const int* in_sizes, int n_in,
                              void* d_out, int out_size, void* d_ws, size_t ws_size,
                              hipStream_t stream) {
    const float* f = (const float*)d_in[0];
    char* ws = (char*)d_ws;
    char* nF        = ws;
    float* partialW = (float*)(ws + OFF_PART);
    float* sposPart = (float*)(ws + OFF_SPOS);

    prep_k<<<PREPBLKS, 256, 0, stream>>>(f, nF, sposPart, (float*)d_out);
    dim3 grid(CHUNKS, YG);
    main_k<<<grid, 256, 0, stream>>>(nF, partialW);
    final_k<<<Nrows / 256, 256, 0, stream>>>(partialW, sposPart, (float*)d_out);
}

// Round 14
// 78.644 us; speedup vs baseline: 1.1132x; 1.1132x over previous
//
#include <hip/hip_runtime.h>
#include <hip/hip_bf16.h>
#include <math.h>

// SupConLoss, B=4096 V=2 D=128, N=8192.
// loss = (1/N) [ sum_i log(sum_{j!=i} exp(n_i.n_j/T)) - 2*sum_b spos_b ]
// Round 14: R11 base (best, 78.3us) +
//  (a) 2 tiles per barrier: 4 barrier drains instead of 8, LDS 36 KB keeps
//      4 blocks/CU (R13's 64 KB -> 2 blocks/CU was the regression cause).
//  (b) sqrt(SCALE) folded into nF at prep: epilogue = exp2 + add only
//      (s = (sqS*a).(sqS*b) = SCALE * a.b; symmetry & col-sums preserved).

constexpr int   Bsz   = 4096;
constexpr int   Nrows = 8192;
constexpr int   Dd    = 128;
constexpr float TEMPf = 0.07f;
constexpr float EPSN  = 1e-8f;
constexpr float SCALE = 1.4426950408889634f / 0.07f;  // log2(e)/T
constexpr float LN2   = 0.6931471805599453f;

constexpr int CHUNKS     = 32;                 // col chunks (grid.x)
constexpr int CHUNK_COLS = Nrows / CHUNKS;     // 256
constexpr int TILES      = CHUNK_COLS / 32;    // 8 col-groups of 32
constexpr int STAGES     = TILES / 2;          // 4 barrier stages (2 tiles each)
constexpr int ROWS_BLK   = 256;                // rows per block (4 waves x 64)
constexpr int YG         = Nrows / ROWS_BLK;   // 32 (grid.y)
constexpr int PREPBLKS   = Bsz / 4;            // 1024

typedef __attribute__((ext_vector_type(8)))  short bf16x8;   // 8 bf16 = 4 VGPRs
typedef __attribute__((ext_vector_type(16))) float floatx16; // MFMA 32x32 C/D

// Fragment-major n: row r = g*32+lo stores its 256 B at
// g*8192 + kc*1024 + hi*512 + lo*16; wave fragment load (g,kc) =
// base + g*8192 + kc*1024 + lane*16 (coalesced 1 KB; DMA lane order matches).

// ws layout (bytes):
//   0x000000  nF   fragment-major bf16 sqrt(SCALE)*n   2 MB
//   0x200000  partial f32[32][8192]                    1 MB
//   0x300000  sposPart f32[1024]                       4 KB
constexpr size_t OFF_PART = 0x200000;
constexpr size_t OFF_SPOS = 0x300000;

__device__ __forceinline__ void gld_lds16(const void* g, void* l) {
    __builtin_amdgcn_global_load_lds(
        (const __attribute__((address_space(1))) void*)g,
        (__attribute__((address_space(3))) void*)l, 16, 0, 0);
}

// ------------- prep: normalize, scale by sqrt(SCALE) -> nF; spos sums ----------
__global__ void prep_k(const float* __restrict__ f,
                       char* __restrict__ nF,
                       float* __restrict__ sposPart,
                       float* __restrict__ out) {
    __shared__ float sred[4];
    int tid  = threadIdx.x;
    int wid  = tid >> 6;
    int lane = tid & 63;
    int b    = blockIdx.x * 4 + wid;
    if (blockIdx.x == 0 && tid == 0) out[0] = 0.f;   // final_k accumulates

    const float sqS = sqrtf(SCALE);                   // folded into both operands
    const float* s0 = f + (size_t)(b * 2) * Dd;       // features[b, 0, :]
    float2 x = *(const float2*)(s0 + lane * 2);       // view 0
    float2 y = *(const float2*)(s0 + Dd + lane * 2);  // view 1
    float ss0 = x.x * x.x + x.y * x.y;
    float ss1 = y.x * y.x + y.y * y.y;
    float dt  = x.x * y.x + x.y * y.y;
    #pragma unroll
    for (int off = 32; off; off >>= 1) {
        ss0 += __shfl_xor(ss0, off);
        ss1 += __shfl_xor(ss1, off);
        dt  += __shfl_xor(dt,  off);
    }
    float inv0 = sqS / fmaxf(sqrtf(ss0), EPSN);
    float inv1 = sqS / fmaxf(sqrtf(ss1), EPSN);

    // lane holds k = 2*lane..2*lane+1 -> piece (kc=lane>>3, hi=(lane>>2)&1)
    size_t poff = (size_t)(lane >> 3) * 1024 + ((lane >> 2) & 1) * 512
                + (lane & 3) * 4;

    __hip_bfloat162 h;
    h.x = __float2bfloat16(x.x * inv0);
    h.y = __float2bfloat16(x.y * inv0);
    *(__hip_bfloat162*)(nF + (size_t)(b >> 5) * 8192 + (b & 31) * 16 + poff) = h;
    int r1 = Bsz + b;
    h.x = __float2bfloat16(y.x * inv1);
    h.y = __float2bfloat16(y.y * inv1);
    *(__hip_bfloat162*)(nF + (size_t)(r1 >> 5) * 8192 + (r1 & 31) * 16 + poff) = h;

    if (lane == 0) {
        float i0 = 1.0f / fmaxf(sqrtf(ss0), EPSN);
        float i1 = 1.0f / fmaxf(sqrtf(ss1), EPSN);
        sred[wid] = dt * i0 * i1 / TEMPf;
    }
    __syncthreads();
    if (tid == 0) sposPart[blockIdx.x] = sred[0] + sred[1] + sred[2] + sred[3];
}

// ------------- main: async-LDS GEMM, 2 tiles/barrier, exp2, col sums -----------
// Grid (32 chunks, 32 row-groups). Per stage: DMA 16 KB (2 tiles) into the
// alternate buffer, ONE barrier, compute 2 tiles (32 MFMA + 64 exp2 / wave).
// LDS 36 KB -> 4 blocks/CU co-resident (16 waves/CU).
__global__ __launch_bounds__(256, 3)
void main_k(const char* __restrict__ nF, float* __restrict__ partial) {
    __shared__ char  bufs[2][2][8192];   // 32 KB: [stage parity][tile][frag data]
    __shared__ float colred[4][256];     // 4 KB
    const int tid  = threadIdx.x;
    const int wid  = tid >> 6;
    const int lane = tid & 63;
    const int lo   = lane & 31;
    const int hi   = lane >> 5;
    const int gy   = blockIdx.y;
    const int rbase = gy * ROWS_BLK + wid * 64;          // wave's 64 rows
    const int cbase = blockIdx.x * CHUNK_COLS;           // 256-aligned
    const int cg0   = cbase >> 5;                        // first col group

    // A fragments: two 32-row groups, 8 coalesced 1 KB loads each (64 VGPRs)
    bf16x8 afrag[2][8];
    #pragma unroll
    for (int s = 0; s < 2; s++) {
        const char* ag = nF + (size_t)((rbase + s * 32) >> 5) * 8192 + lane * 16;
        #pragma unroll
        for (int kc = 0; kc < 8; kc++)
            afrag[s][kc] = *(const bf16x8*)(ag + kc * 1024);
    }

    // stage 0: 16 fragment-units (2 tiles x 8 kc); wave w DMAs units 4w..4w+3
    {
        const char* gsrc = nF + (size_t)cg0 * 8192;
        #pragma unroll
        for (int j = 0; j < 4; j++) {
            int u = wid * 4 + j;                 // u = tile*8 + kc
            gld_lds16(gsrc + (size_t)u * 1024 + lane * 16,
                      &bufs[0][u >> 3][(u & 7) * 1024]);
        }
    }

    floatx16 zero = {};

    #pragma unroll 1
    for (int st = 0; st < STAGES; st++) {
        __syncthreads();   // stage st DMA drained; prev buffer free
        if (st + 1 < STAGES) {
            const char* gn = nF + (size_t)(cg0 + (st + 1) * 2) * 8192;
            char* dst0 = bufs[(st + 1) & 1][0];
            char* dst1 = bufs[(st + 1) & 1][1];
            #pragma unroll
            for (int j = 0; j < 4; j++) {
                int u = wid * 4 + j;
                gld_lds16(gn + (size_t)u * 1024 + lane * 16,
                          (u >> 3) ? dst1 + (u & 7) * 1024
                                   : dst0 + (u & 7) * 1024);
            }
        }

        #pragma unroll
        for (int half = 0; half < 2; half++) {
            const int t = st * 2 + half;
            const char* buf = bufs[st & 1][half];
            floatx16 acc0 = zero, acc1 = zero;
            #pragma unroll
            for (int kc = 0; kc < 8; kc++) {
                bf16x8 bf = *(const bf16x8*)&buf[kc * 1024 + lane * 16];
                acc0 = __builtin_amdgcn_mfma_f32_32x32x16_bf16(afrag[0][kc], bf, acc0, 0, 0, 0);
                acc1 = __builtin_amdgcn_mfma_f32_32x32x16_bf16(afrag[1][kc], bf, acc1, 0, 0, 0);
            }

            // epilogue: exp2 (SCALE folded into nF), diag mask, COLUMN sums
            const int cb32 = cbase + t * 32;
            float cs = 0.f;
            #pragma unroll
            for (int s = 0; s < 2; s++) {
                const floatx16& acc = s ? acc1 : acc0;
                if (cb32 == rbase + s * 32) {     // wave-uniform, rare
                    #pragma unroll
                    for (int r = 0; r < 16; r++) {
                        float e = __builtin_amdgcn_exp2f(acc[r]);
                        // C/D layout: col=lo, row_local=(r&3)+8*(r>>2)+4*hi
                        if (lo == ((r & 3) + 8 * (r >> 2) + 4 * hi)) e = 0.f;
                        cs += e;
                    }
                } else {
                    #pragma unroll
                    for (int r = 0; r < 16; r++)
                        cs += __builtin_amdgcn_exp2f(acc[r]);
                }
            }
            cs += __shfl_xor(cs, 32);             // fold the two row-half lanes
            if (hi == 0) colred[wid][t * 32 + lo] = cs;
        }
    }

    __syncthreads();
    // cross-wave: block's col sums over its 256-row stripe, coalesced store
    float v = colred[0][tid] + colred[1][tid] + colred[2][tid] + colred[3][tid];
    partial[(size_t)gy * Nrows + cbase + tid] = v;
}

// ------------- finalize: 32 blocks; atomicAdd the scalar -----------------------
// se[col] = sum_gy partial[gy][col]  (col sum == row sum of exp matrix)
__global__ __launch_bounds__(256)
void final_k(const float* __restrict__ partial, const float* __restrict__ sposPart,
             float* __restrict__ out) {
    __shared__ float red[4];
    int tid = threadIdx.x;
    int r = blockIdx.x * 256 + tid;
    float se = 0.f;
    #pragma unroll
    for (int p = 0; p < YG; p++) se += partial[(size_t)p * Nrows + r];
    float acc = __builtin_amdgcn_logf(se) * LN2;   // v_log_f32 is log2
    if (tid < 32) acc -= 2.f * sposPart[blockIdx.x * 32 + tid];
    #pragma unroll
    for (int off = 32; off; off >>= 1) acc += __shfl_xor(acc, off);
    if ((tid & 63) == 0) red[tid >> 6] = acc;
    __syncthreads();
    if (tid == 0)
        atomicAdd(out, (red[0] + red[1] + red[2] + red[3]) / (float)Nrows);
}

extern "C" void kernel_launch(void* const* d_in, const int* in_sizes, int n_in,
                              void* d_out, int out_size, void* d_ws, size_t ws_size,
                              hipStream_t stream) {
    const float* f = (const float*)d_in[0];
    char* ws = (char*)d_ws;
    char* nF        = ws;
    float* partial  = (float*)(ws + OFF_PART);
    float* sposPart = (float*)(ws + OFF_SPOS);

    prep_k<<<PREPBLKS, 256, 0, stream>>>(f, nF, sposPart, (float*)d_out);
    dim3 grid(CHUNKS, YG);
    main_k<<<grid, 256, 0, stream>>>(nF, partial);
    final_k<<<Nrows / 256, 256, 0, stream>>>(partial, sposPart, (float*)d_out);
}